// Round 4
// baseline (156.986 us; speedup 1.0000x reference)
//
#include <hip/hip_runtime.h>

// VectorQuantizer R3: input (16,64,64,64) f32 channel-first, codebook (1024,64) f32.
// out = [quantized (16,64,64,64) f32 | indices (16,64,64) as f32].
//
// A = codebook (rows=cw), B = tokens (cols) in mfma_f32_32x32x16_f16:
//   - prep bakes (-2*c) into f16 A-fragments, plus a 5th k-chunk carrying
//     e_sq as split f16 (e_hi+e_lo) against a constant-ones B5 fragment,
//     so acc[r] == score = e_sq - 2*dot directly out of the MFMA chain.
//   - per-score tracking: pack slot(tile,r) into low 8 mantissa bits
//     (1 v_and_or) + fmed3 2nd-best + fmin best = 3 VALU/score.
//   - per-token reduce: 16 in-register rows + one shfl_xor(32); 2 half-K
//     waves merge via tiny LDS. Near-ties (gap < EPS) get exact fp32
//     full-K rescan => matches reference argmin incl. first-index ties.
// Wave = 64 tokens x 512 cw; block = 4 waves = 128 tokens; grid = 512.

typedef _Float16 v8h  __attribute__((ext_vector_type(8)));
typedef float    v16f __attribute__((ext_vector_type(16)));

constexpr int   D         = 64;
constexpr int   K         = 1024;
constexpr int   HW        = 4096;
constexpr int   DHW       = D * HW;
constexpr int   OUT_ELEMS = 16 * DHW;
constexpr float EPS       = 0.065f;

// CH: 32 tiles x 5 chunks (4 data + 1 esq) x 64 lanes x 8 f16 = 160 KB.
// frag f = t*5+kc; CH[f*512 + lane*8 + j]:
//   kc<4 : A[row = t*32 + (lane&31)][k = kc*16 + (lane>>5)*8 + j] = -2*c
//   kc==4: lh==0: j0=e_hi, j1=e_lo, else 0 (pairs with B5 = ones at k=0,1)

__global__ __launch_bounds__(256) void vq_prep(
    const float* __restrict__ cb, _Float16* __restrict__ CH, float* __restrict__ esq)
{
    const int blk = blockIdx.x, tid = threadIdx.x;
    if (blk < 40) {
        const int gid  = blk * 256 + tid;          // [0, 10240)
        const int lane = gid & 63;
        const int fid  = gid >> 6;                 // [0, 160)
        const int t    = fid / 5;
        const int kc   = fid - 5 * t;
        const int l31  = lane & 31;
        const int lh   = lane >> 5;
        const int cw   = t * 32 + l31;
        v8h h;
        if (kc < 4) {
            const float* src = cb + cw * D + kc * 16 + lh * 8;
            #pragma unroll
            for (int j = 0; j < 8; ++j) h[j] = (_Float16)(-2.0f * src[j]);
        } else {
            #pragma unroll
            for (int j = 0; j < 8; ++j) h[j] = (_Float16)0.0f;
            if (lh == 0) {
                const float4* c4 = (const float4*)(cb + cw * D);
                float a0 = 0.f, a1 = 0.f, a2 = 0.f, a3 = 0.f;
                #pragma unroll
                for (int j = 0; j < 16; ++j) {
                    const float4 c = c4[j];
                    a0 = fmaf(c.x, c.x, a0);
                    a1 = fmaf(c.y, c.y, a1);
                    a2 = fmaf(c.z, c.z, a2);
                    a3 = fmaf(c.w, c.w, a3);
                }
                const float e   = (a0 + a1) + (a2 + a3);
                const _Float16 ehi = (_Float16)e;
                h[0] = ehi;
                h[1] = (_Float16)(e - (float)ehi);
            }
        }
        *(v8h*)(CH + (size_t)fid * 512 + lane * 8) = h;
    } else {
        const int cw = (blk - 40) * 256 + tid;     // exact f32 e_sq for rescan
        const float4* c4 = (const float4*)(cb + cw * D);
        float a0 = 0.f, a1 = 0.f, a2 = 0.f, a3 = 0.f;
        #pragma unroll
        for (int j = 0; j < 16; ++j) {
            const float4 c = c4[j];
            a0 = fmaf(c.x, c.x, a0);
            a1 = fmaf(c.y, c.y, a1);
            a2 = fmaf(c.z, c.z, a2);
            a3 = fmaf(c.w, c.w, a3);
        }
        esq[cw] = (a0 + a1) + (a2 + a3);
    }
}

__global__ __launch_bounds__(256, 2) void vq_scan(
    const float* __restrict__ input,
    const float* __restrict__ codebook,
    const _Float16* __restrict__ CH,
    const float* __restrict__ esq,
    float* __restrict__ out)
{
    __shared__ float    s_pv[2][2][64];   // [half][group][token-in-group] best (packed)
    __shared__ float    s_p2[2][2][64];   // second best
    __shared__ int      s_pk[2][2][64];   // best cw
    __shared__ int      s_idx[128];
    __shared__ unsigned s_mask[4];
    __shared__ float    s_x[4][64];       // rescan x staging per wave

    const int tid  = threadIdx.x;
    const int lane = tid & 63;
    const int q    = __builtin_amdgcn_readfirstlane(tid >> 6);
    const int g    = q >> 1;              // token group (0/1): 64 tokens each
    const int h    = q & 1;               // K half (0/1): cw [h*512, h*512+512)
    const int l31  = lane & 31;
    const int lh   = lane >> 5;
    const int tok0 = blockIdx.x * 128;
    const int b    = tok0 >> 12;
    const int hwb  = tok0 & 4095;

    if (tid < 4) s_mask[tid] = 0u;

    // ---- B fragments: 2 col-tiles x 4 k-chunks of this wave's 64 tokens ----
    // B[k = kc*16 + lh*8 + j][col = ct*32 + l31]
    v8h bt[2][4];
    {
        const float* xb = input + (size_t)b * DHW + hwb + g * 64;
        #pragma unroll
        for (int ct = 0; ct < 2; ++ct)
            #pragma unroll
            for (int kc = 0; kc < 4; ++kc) {
                const int d0 = kc * 16 + lh * 8;
                #pragma unroll
                for (int j = 0; j < 8; ++j)
                    bt[ct][kc][j] = (_Float16)xb[(size_t)(d0 + j) * HW + ct * 32 + l31];
            }
    }

    // B5: ones at k=0,1 (pairs with esq chunk)
    v8h b5;
    #pragma unroll
    for (int j = 0; j < 8; ++j) b5[j] = (_Float16)0.0f;
    if (lh == 0) { b5[0] = (_Float16)1.0f; b5[1] = (_Float16)1.0f; }

    v16f Z = {0,0,0,0,0,0,0,0,0,0,0,0,0,0,0,0};

    const float INF = __builtin_huge_valf();
    float bv0 = INF, b20 = INF, bv1 = INF, b21 = INF;

    const v8h* Abase = (const v8h*)CH + lane;

    #pragma unroll 4
    for (int t = 0; t < 16; ++t) {
        const int T = h * 16 + t;
        const v8h* Ap = Abase + (size_t)(T * 5) * 64;
        const v8h a0 = Ap[0], a1 = Ap[64], a2 = Ap[128], a3 = Ap[192], a5 = Ap[256];

        v16f acc0 = __builtin_amdgcn_mfma_f32_32x32x16_f16(a5, b5, Z, 0, 0, 0);
        v16f acc1 = __builtin_amdgcn_mfma_f32_32x32x16_f16(a5, b5, Z, 0, 0, 0);
        acc0 = __builtin_amdgcn_mfma_f32_32x32x16_f16(a0, bt[0][0], acc0, 0, 0, 0);
        acc1 = __builtin_amdgcn_mfma_f32_32x32x16_f16(a0, bt[1][0], acc1, 0, 0, 0);
        acc0 = __builtin_amdgcn_mfma_f32_32x32x16_f16(a1, bt[0][1], acc0, 0, 0, 0);
        acc1 = __builtin_amdgcn_mfma_f32_32x32x16_f16(a1, bt[1][1], acc1, 0, 0, 0);
        acc0 = __builtin_amdgcn_mfma_f32_32x32x16_f16(a2, bt[0][2], acc0, 0, 0, 0);
        acc1 = __builtin_amdgcn_mfma_f32_32x32x16_f16(a2, bt[1][2], acc1, 0, 0, 0);
        acc0 = __builtin_amdgcn_mfma_f32_32x32x16_f16(a3, bt[0][3], acc0, 0, 0, 0);
        acc1 = __builtin_amdgcn_mfma_f32_32x32x16_f16(a3, bt[1][3], acc1, 0, 0, 0);

        // acc[r] IS the score. Pack slot into low 8 mantissa bits, track top-2.
        #pragma unroll
        for (int r = 0; r < 16; ++r) {
            const unsigned slot = (unsigned)((t << 4) | r);
            const float s0 = __uint_as_float((__float_as_uint(acc0[r]) & 0xFFFFFF00u) | slot);
            b20 = __builtin_amdgcn_fmed3f(s0, bv0, b20);
            bv0 = fminf(bv0, s0);
            const float s1 = __uint_as_float((__float_as_uint(acc1[r]) & 0xFFFFFF00u) | slot);
            b21 = __builtin_amdgcn_fmed3f(s1, bv1, b21);
            bv1 = fminf(bv1, s1);
        }
    }

    // ---- cross-half-row merge (lane <-> lane^32), decode cw, stash to LDS ----
    #pragma unroll
    for (int ct = 0; ct < 2; ++ct) {
        const float bv = ct ? bv1 : bv0;
        const float b2 = ct ? b21 : b20;
        const float obv = __shfl_xor(bv, 32, 64);
        const float ob2 = __shfl_xor(b2, 32, 64);
        const float B1 = fminf(bv, obv);
        const float B2 = fminf(fmaxf(bv, obv), fminf(b2, ob2));
        const int   lho = (obv < bv) ? (lh ^ 1) : lh;   // tie keeps own (lanes<32: lh=0)
        const unsigned slot = __float_as_uint(B1) & 255u;
        const int r  = slot & 15;
        const int tt = slot >> 4;
        const int cw = (h * 16 + tt) * 32 + (r & 3) + 8 * (r >> 2) + 4 * lho;
        if (lane < 32) {
            s_pv[h][g][ct * 32 + lane] = B1;
            s_p2[h][g][ct * 32 + lane] = B2;
            s_pk[h][g][ct * 32 + lane] = cw;
        }
    }
    __syncthreads();

    // ---- merge the two K-halves per token; flag near-ties ----
    if (tid < 128) {
        const int g2 = tid >> 6, tk = tid & 63;
        const float v0 = s_pv[0][g2][tk], v1 = s_pv[1][g2][tk];
        const bool  w1 = v1 < v0;                        // tie -> h=0 (lower cw)
        const float B1 = fminf(v0, v1);
        const float B2 = fminf(fmaxf(v0, v1), fminf(s_p2[0][g2][tk], s_p2[1][g2][tk]));
        s_idx[tid] = w1 ? s_pk[1][g2][tk] : s_pk[0][g2][tk];
        if (B2 - B1 < EPS) atomicOr(&s_mask[tid >> 5], 1u << (tid & 31));
    }
    __syncthreads();

    // ---- exact fp32 rescan for uncertain tokens (rare), wave-parallel ----
    {
        int ui = 0;
        for (int w = 0; w < 4; ++w) {
            unsigned m = s_mask[w];
            while (m) {
                const int bit = __ffs(m) - 1;
                m &= m - 1;
                const int tl = w * 32 + bit;
                if ((ui & 3) == q) {
                    const int hw = hwb + tl;
                    s_x[q][lane] = input[(size_t)b * DHW + (size_t)lane * HW + hw];
                    const float4* xs4 = (const float4*)s_x[q];
                    float bestv = INF; int bestk = K;
                    for (int rr = 0; rr < 16; ++rr) {
                        const int k = lane + rr * 64;
                        const float4* c4 = (const float4*)(codebook + (size_t)k * D);
                        float a0 = 0.f, a1 = 0.f, a2 = 0.f, a3 = 0.f;
                        #pragma unroll
                        for (int j = 0; j < 16; ++j) {
                            const float4 c  = c4[j];
                            const float4 xv = xs4[j];
                            a0 = fmaf(xv.x, c.x, a0);
                            a1 = fmaf(xv.y, c.y, a1);
                            a2 = fmaf(xv.z, c.z, a2);
                            a3 = fmaf(xv.w, c.w, a3);
                        }
                        const float s = fmaf(-2.0f, (a0 + a1) + (a2 + a3), esq[k]);
                        if (s < bestv) { bestv = s; bestk = k; }   // ascending k
                    }
                    #pragma unroll
                    for (int off = 32; off >= 1; off >>= 1) {
                        const float ov = __shfl_xor(bestv, off, 64);
                        const int   ok = __shfl_xor(bestk, off, 64);
                        if (ov < bestv || (ov == bestv && ok < bestk)) { bestv = ov; bestk = ok; }
                    }
                    if (lane == 0) s_idx[tl] = bestk;
                }
                ++ui;
            }
        }
    }
    __syncthreads();

    // ---- epilogue: gather codebook row, coalesced per-channel stores ----
    {
        const int tkn = tid & 127;
        const int dq  = tid >> 7;                       // 0/1: channels [dq*32, dq*32+32)
        const int idx = s_idx[tkn];
        const int hw  = hwb + tkn;
        const float4* c4 = (const float4*)(codebook + (size_t)idx * D + dq * 32);
        float* op = out + (size_t)b * DHW + (size_t)dq * 32 * HW + hw;
        #pragma unroll
        for (int j = 0; j < 8; ++j) {
            const float4 c = c4[j];
            op[(size_t)(4 * j + 0) * HW] = c.x;
            op[(size_t)(4 * j + 1) * HW] = c.y;
            op[(size_t)(4 * j + 2) * HW] = c.z;
            op[(size_t)(4 * j + 3) * HW] = c.w;
        }
        if (tid < 128) out[OUT_ELEMS + tok0 + tid] = (float)s_idx[tid];
    }
}

extern "C" void kernel_launch(void* const* d_in, const int* in_sizes, int n_in,
                              void* d_out, int out_size, void* d_ws, size_t ws_size,
                              hipStream_t stream) {
    const float* input    = (const float*)d_in[0];
    const float* codebook = (const float*)d_in[1];
    float* out            = (float*)d_out;

    _Float16* CH  = (_Float16*)d_ws;                   // 163840 B
    float*    esq = (float*)((char*)d_ws + 163840);    // 4096 B

    vq_prep<<<44, 256, 0, stream>>>(codebook, CH, esq);
    vq_scan<<<512, 256, 0, stream>>>(input, codebook, CH, esq, out);
}